// Round 12
// baseline (44.911 us; speedup 1.0000x reference)
//
#include <hip/hip_runtime.h>
#include <hip/hip_bf16.h>

#define EPS 1e-6f

typedef __attribute__((ext_vector_type(4))) float f32x4;

// pack 4 floats into 4 fp8-e4m3 bytes (k-order: x->byte0 .. w->byte3)
__device__ inline unsigned int pack_fp8x4(float x, float y, float z, float w) {
  int r = 0;
  r = __builtin_amdgcn_cvt_pk_fp8_f32(x, y, r, false);  // bytes 0,1
  r = __builtin_amdgcn_cvt_pk_fp8_f32(z, w, r, true);   // bytes 2,3
  return (unsigned int)r;
}

// ---------------------------------------------------------------------------
// Kernel A: per-speaker precompute (192 threads, float4-vectorized).
// Writes: a8[i][d] = fp8e4m3(dvec[i][d]/||dvec_i||)      (10240 x 768)
//         c8[n][d] = fp8e4m3(ctrd[n][d]/||ctrd_n||)      (1024 x 768)
//         simown[i] = fp32 cosine(dvec_i, excl-centroid) (10240, exact fp32)
// Also zeroes rowsum[10240] and out[0].   (verified rounds 6-11)
// ---------------------------------------------------------------------------
__global__ void __launch_bounds__(192) ge2e_pre(
    const float* __restrict__ dv, unsigned int* __restrict__ a8u,
    unsigned int* __restrict__ c8u, float* __restrict__ simown,
    float* __restrict__ rowsum, float* __restrict__ out) {
  const int n = blockIdx.x, t = threadIdx.x;  // t in [0,192): owns dims 4t..4t+3
  if (n == 0 && t == 0) out[0] = 0.f;  // consumed by ge2e_final (stream-ordered)
  const float* base = dv + (size_t)n * 7680;
  float4 v[10];
  float4 s4 = make_float4(0.f, 0.f, 0.f, 0.f);
#pragma unroll
  for (int m = 0; m < 10; ++m) {
    v[m] = *reinterpret_cast<const float4*>(&base[m * 768 + 4 * t]);
    s4.x += v[m].x; s4.y += v[m].y; s4.z += v[m].z; s4.w += v[m].w;
  }
  float part[21];
#pragma unroll
  for (int m = 0; m < 10; ++m) {
    part[m]      = v[m].x * s4.x + v[m].y * s4.y + v[m].z * s4.z + v[m].w * s4.w;
    part[10 + m] = v[m].x * v[m].x + v[m].y * v[m].y + v[m].z * v[m].z + v[m].w * v[m].w;
  }
  part[20] = s4.x * s4.x + s4.y * s4.y + s4.z * s4.z + s4.w * s4.w;
#pragma unroll
  for (int k = 0; k < 21; ++k) {
#pragma unroll
    for (int off = 32; off >= 1; off >>= 1) part[k] += __shfl_xor(part[k], off);
  }
  __shared__ float red[3][21];
  __shared__ float bc[21];
  const int lane = t & 63, wid = t >> 6;
  if (lane == 0) {
#pragma unroll
    for (int k = 0; k < 21; ++k) red[wid][k] = part[k];
  }
  __syncthreads();
  if (t < 21) bc[t] = red[0][t] + red[1][t] + red[2][t];
  __syncthreads();
  const float ss = bc[20];
  // centroid = sums/10; cnorm = max(|ctrd|,eps) -> normalize sums by max(|sums|,10eps)
  const float rc = 1.0f / fmaxf(sqrtf(ss), 10.0f * EPS);
  c8u[n * 192 + t] = pack_fp8x4(s4.x * rc, s4.y * rc, s4.z * rc, s4.w * rc);
#pragma unroll
  for (int m = 0; m < 10; ++m) {
    float rd = 1.0f / fmaxf(sqrtf(bc[10 + m]), EPS);
    a8u[(size_t)(n * 10 + m) * 192 + t] =
        pack_fp8x4(v[m].x * rd, v[m].y * rd, v[m].z * rd, v[m].w * rd);
  }
  if (t < 10) {
    float dot = bc[t], sq = bc[10 + t];
    float dn = fmaxf(sqrtf(sq), EPS);
    float en = fmaxf(sqrtf(fmaxf(ss - 2.f * dot + sq, 0.f)) * (1.0f / 9.0f), EPS);
    simown[n * 10 + t] = ((dot - sq) * (1.0f / 9.0f)) / (dn * en);
    rowsum[n * 10 + t] = 0.f;  // accumulated by ge2e_gemm's final flush
  }
}

// ---------------------------------------------------------------------------
// Kernel B: fp8 MFMA GEMM (10240x1024x768), ZERO-RESTAGE structure:
//   * B (this block's 128-col panel) loaded ONCE into REGISTERS:
//     bReg[2][24] = 48 i64 frags = 96 VGPR per thread. Staged coalesced in
//     two 64-col passes through the A-LDS area, read out XOR-swizzled.
//   * A streamed as FULL-K 32-row tiles (24 KB), double-buffered with
//     counted vmcnt(3) -- a full round (~900cy) of flight per tile; the
//     K-inner loop is 24 ds_read_b64 + 48 MFMA on registers, NO barriers,
//     NO waits. Only 2 barriers per round, 10 rounds (vs 24 K-step pairs
//     in rounds 5-11, whose stage-drain-barrier path capped gemm ~28us).
//   * Per-round row-sums: exp -> 16-lane shfl -> LDS ds_add (lgkmcnt domain,
//     keeps vmcnt(3) counting exact); ONE global-atomic flush at the end.
//   * Diagonal exits the hot loop: owning lane stores raw GEMM diag value;
//     ge2e_final corrects rowsum by -exp(w*diag)+exp(w*simown).
//   * XOR swizzle slot^=(row&7) on stage SOURCE and ds_read (rule #21).
// Grid 8 col-blocks x 32 row-parts = 256 = 1 block/CU exact; 8 waves 2Mx4N,
// wave 16x32, acc 4 chains = 16 VGPR; ~145 VGPR under (512,2) cap 256.
// LDS = 48 KB A-dbuf + rowAcc. XCD swizzle 256 = 8x32.
// ---------------------------------------------------------------------------
__global__ void __launch_bounds__(512, 2) ge2e_gemm(
    const unsigned char* __restrict__ a8, const unsigned char* __restrict__ c8,
    const float* __restrict__ wp, float* __restrict__ rowsum,
    float* __restrict__ diag) {
  __shared__ __align__(16) unsigned char As[49152];  // 2 x 24KB A dbuf; B prologue area
  __shared__ float rowAcc[320];
  const int t = threadIdx.x;
  const int lane = t & 63, wid = t >> 6;
  const int bx = blockIdx.x;
  const int wg = (bx & 7) * 32 + (bx >> 3);  // bijective XCD swizzle, 256=8x32
  const int rp = wg >> 3, cb = wg & 7;
  const int rowPart = rp * 320, col0 = cb * 128;
  const int wm = wid >> 2, wn = wid & 3;     // wave tile: 16 rows x 32 cols
  const int l15 = lane & 15, lg = lane >> 4;
  const float wv = wp[0];

  if (t < 320) rowAcc[t] = 0.f;

  // ---------- B prologue: two 64-col coalesced passes -> registers ----------
  long long bReg[2][24];
#pragma unroll
  for (int h = 0; h < 2; ++h) {
#pragma unroll
    for (int j = 0; j < 6; ++j) {
      const int cidx = (wid * 6 + j) * 64 + lane;     // 0..3071 (16B chunks)
      const int col = cidx / 48, slot = cidx - col * 48;
      const int srcSlot = slot ^ (col & 7);           // inverse-swizzled source
      const unsigned char* src =
          c8 + (size_t)(col0 + h * 64 + col) * 768 + srcSlot * 16;
      __builtin_amdgcn_global_load_lds(
          (const __attribute__((address_space(1))) unsigned int*)src,
          (__attribute__((address_space(3))) unsigned int*)&As[(wid * 6 + j) * 1024],
          16, 0, 0);
    }
    asm volatile("s_waitcnt vmcnt(0)" ::: "memory");
    __syncthreads();
    if ((wn >> 1) == h) {   // this wave's cols live in half h
#pragma unroll
      for (int cs = 0; cs < 2; ++cs) {
        const int row = (wn & 1) * 32 + cs * 16 + l15;
#pragma unroll
        for (int kk = 0; kk < 24; ++kk) {
          const int slotK = 2 * kk + (lg >> 1);
          bReg[cs][kk] = *(const long long*)
              &As[row * 768 + ((slotK ^ (row & 7)) << 4) + (lg & 1) * 8];
        }
      }
    }
    __syncthreads();  // drains lgkm: reads done before next overwrite
  }

  // ---------- A streaming: 10 full-K rounds of 32 rows ----------
  auto STAGE_A = [&](int buf, int s) {
#pragma unroll
    for (int j = 0; j < 3; ++j) {
      const int cidx = (wid * 3 + j) * 64 + lane;     // 0..1535
      const int row = cidx / 48, slot = cidx - row * 48;
      const int srcSlot = slot ^ (row & 7);
      const unsigned char* src =
          a8 + (size_t)(rowPart + s * 32 + row) * 768 + srcSlot * 16;
      __builtin_amdgcn_global_load_lds(
          (const __attribute__((address_space(1))) unsigned int*)src,
          (__attribute__((address_space(3))) unsigned int*)
              &As[buf * 24576 + (wid * 3 + j) * 1024],
          16, 0, 0);
    }
  };

  const int aRow = wm * 16 + l15;
  const int aOff0 = aRow * 768 + (lg & 1) * 8;
  const int ar7 = aRow & 7, ac0 = lg >> 1;

  STAGE_A(0, 0);
  for (int s = 0; s < 10; ++s) {
    const int buf = s & 1;
    if (s < 9) {
      STAGE_A(buf ^ 1, s + 1);
      // tile s's 3 loads are the oldest; tile s+1's 3 stay in flight
      asm volatile("s_waitcnt vmcnt(3)" ::: "memory");
    } else {
      asm volatile("s_waitcnt vmcnt(0)" ::: "memory");
    }
    __builtin_amdgcn_s_barrier();

    f32x4 acc[2][2];  // [fc][kk-parity] -- 4 independent MFMA chains
#pragma unroll
    for (int fc = 0; fc < 2; ++fc)
#pragma unroll
      for (int p = 0; p < 2; ++p) acc[fc][p] = (f32x4){0.f, 0.f, 0.f, 0.f};

    __builtin_amdgcn_s_setprio(1);
#pragma unroll
    for (int kk = 0; kk < 24; ++kk) {   // full K, no barriers, no waits
      const int slotK = 2 * kk + ac0;
      const long long a = *(const long long*)
          &As[buf * 24576 + aOff0 + ((slotK ^ ar7) << 4)];
      acc[0][kk & 1] = __builtin_amdgcn_mfma_f32_16x16x32_fp8_fp8(
          a, bReg[0][kk], acc[0][kk & 1], 0, 0, 0);
      acc[1][kk & 1] = __builtin_amdgcn_mfma_f32_16x16x32_fp8_fp8(
          a, bReg[1][kk], acc[1][kk & 1], 0, 0, 0);
    }
    __builtin_amdgcn_s_setprio(0);

    // round epilogue: exp row-sums -> LDS ds_add (vmcnt-neutral);
    // raw diagonal value exported for correction in ge2e_final.
#pragma unroll
    for (int r = 0; r < 4; ++r) {
      const int lrow = s * 32 + wm * 16 + lg * 4 + r;
      const int grow = rowPart + lrow;
      const int ownc = grow / 10;
      float sm = 0.f;
#pragma unroll
      for (int fc = 0; fc < 2; ++fc) {
        const int gcol = col0 + wn * 32 + fc * 16 + l15;
        const float vv = acc[fc][0][r] + acc[fc][1][r];
        if (gcol == ownc) diag[grow] = vv;  // rare store (older than next vmcnt wait)
        sm += __expf(wv * vv);
      }
#pragma unroll
      for (int off = 1; off < 16; off <<= 1) sm += __shfl_xor(sm, off, 16);
      if (l15 == 0) atomicAdd(&rowAcc[lrow], sm);
    }
    __builtin_amdgcn_s_barrier();  // buf free for next round's STAGE
  }

  __syncthreads();  // all ds_adds complete
  if (t < 320) atomicAdd(&rowsum[rowPart + t], rowAcc[t]);
}

// ---------------------------------------------------------------------------
// Kernel C: correct the diagonal, then loss_i = log(rowsum') - w*simown_i;
// sum over 10240 into d_out.
// ---------------------------------------------------------------------------
__global__ void __launch_bounds__(256) ge2e_final(
    const float* __restrict__ rowsum, const float* __restrict__ simown,
    const float* __restrict__ diag, const float* __restrict__ wp,
    float* __restrict__ out) {
  const int i = blockIdx.x * 256 + threadIdx.x;  // 0..10239
  const float wv = wp[0];
  const float so = simown[i];
  const float corrected = rowsum[i] - __expf(wv * diag[i]) + __expf(wv * so);
  float loss = logf(corrected) - wv * so;
#pragma unroll
  for (int off = 32; off >= 1; off >>= 1) loss += __shfl_xor(loss, off);
  __shared__ float red[4];
  const int lane = threadIdx.x & 63, wid = threadIdx.x >> 6;
  if (lane == 0) red[wid] = loss;
  __syncthreads();
  if (threadIdx.x == 0) atomicAdd(out, red[0] + red[1] + red[2] + red[3]);
}

extern "C" void kernel_launch(void* const* d_in, const int* in_sizes, int n_in,
                              void* d_out, int out_size, void* d_ws, size_t ws_size,
                              hipStream_t stream) {
  (void)in_sizes; (void)n_in; (void)out_size; (void)ws_size;
  const float* dv = (const float*)d_in[0];
  const float* wp = (const float*)d_in[1];
  // d_in[2] (bias b) cancels exactly in -log_softmax[own]; unused.

  unsigned char* a8 = (unsigned char*)d_ws;                         // 7,864,320 B
  unsigned char* c8 = (unsigned char*)d_ws + 7864320;               //   786,432 B
  float* simown = (float*)((char*)d_ws + 8650752);                  //    40,960 B
  float* rowsum = (float*)((char*)d_ws + 8691712);                  //    40,960 B
  float* diag   = (float*)((char*)d_ws + 8732672);                  //    40,960 B
  float* out = (float*)d_out;

  ge2e_pre<<<1024, 192, 0, stream>>>(dv, (unsigned int*)a8, (unsigned int*)c8,
                                     simown, rowsum, out);
  ge2e_gemm<<<256, 512, 0, stream>>>(a8, c8, wp, rowsum, diag);
  ge2e_final<<<40, 256, 0, stream>>>(rowsum, simown, diag, wp, out);
}